// Round 18
// baseline (376.813 us; speedup 1.0000x reference)
//
#include <hip/hip_runtime.h>
#include <math.h>

#define N_NODES 100000
#define N_EDGES 1250000
#define NGRAPH 256
#define IN_DIM 8
#define DIM 64
#define BN_EPS 1e-5f

#define BSHIFT 9
#define BNODES 512
#define NBUCK 196           // ceil(100000 / 512)
#define BCAP 8192           // fixed bucket capacity (mean 6400, +22 sigma)
#define NBLK_B 256
#define CHUNK 4883          // ceil(1250000 / 256)
#define POOL_ROWS 128
#define NTILES 3125         // N_NODES / 32

typedef unsigned short bf16_t;

static __device__ inline float bf2f(bf16_t u) {
    return __uint_as_float(((unsigned int)u) << 16);
}
static __device__ inline bf16_t f2bf(float f) {
    unsigned int b = __float_as_uint(f);
    b += 0x7fffu + ((b >> 16) & 1u);
    return (bf16_t)(b >> 16);
}

// ------- bucket fill: per-block LDS count -> chunk reservation -> burst writes -------
// bucket_cursor[] is zero-initialized by the big memset; fixed base = b*BCAP.

__global__ void __launch_bounds__(256) k_bfill(const int* __restrict__ src,
                                               const int* __restrict__ dst,
                                               const float2* __restrict__ edge_attr,
                                               int* __restrict__ bucket_cursor,
                                               int2* __restrict__ ebuf) {
    __shared__ int lh[NBUCK], lbase[NBUCK];
    int tid = threadIdx.x;
    if (tid < NBUCK) lh[tid] = 0;
    __syncthreads();
    int e0 = blockIdx.x * CHUNK;
    int e1 = e0 + CHUNK; if (e1 > N_EDGES) e1 = N_EDGES;
    for (int e = e0 + tid; e < e1; e += 256)
        atomicAdd(&lh[dst[e] >> BSHIFT], 1);
    __syncthreads();
    if (tid < NBUCK) {
        lbase[tid] = tid * BCAP + atomicAdd(&bucket_cursor[tid], lh[tid]);
        lh[tid] = 0;
    }
    __syncthreads();
    for (int e = e0 + tid; e < e1; e += 256) {
        int d = dst[e];
        int b = d >> BSHIFT;
        int pos = lbase[b] + atomicAdd(&lh[b], 1);
        int pk = src[e] | ((d & (BNODES - 1)) << 17);  // src<2^17, dlocal<2^9
        ebuf[pos] = make_int2(pk, __float_as_int(edge_attr[e].y));
    }
}

// ------- bucket sort: CSR placement (raw w) + offsets/ends + dinv + fused xscale -------

__global__ void __launch_bounds__(512) k_bsort(
        const int* __restrict__ bucket_cursor, const int2* __restrict__ ebuf,
        int* __restrict__ offsets, int* __restrict__ ends, int2* __restrict__ csr,
        float* __restrict__ dinv, const float* __restrict__ x, float* __restrict__ xs) {
    __shared__ int cnt[BNODES];
    __shared__ float wsum[BNODES];
    __shared__ int tsum[BNODES];
    int tid = threadIdx.x;
    int b = blockIdx.x;
    int nbase = b * BNODES;
    int nloc = N_NODES - nbase; if (nloc > BNODES) nloc = BNODES;
    cnt[tid] = 0; wsum[tid] = 0.0f;
    __syncthreads();
    int e0 = b * BCAP;
    int ecnt = bucket_cursor[b];
    for (int e = e0 + tid; e < e0 + ecnt; e += 512) {
        int2 p = ebuf[e];
        int dl = p.x >> 17;
        atomicAdd(&cnt[dl], 1);
        atomicAdd(&wsum[dl], __int_as_float(p.y));
    }
    __syncthreads();
    int myc = cnt[tid];
    tsum[tid] = myc;
    __syncthreads();
    for (int off = 1; off < 512; off <<= 1) {
        int add = (tid >= off) ? tsum[tid - off] : 0;
        __syncthreads();
        tsum[tid] += add;
        __syncthreads();
    }
    int excl = tsum[tid] - myc;
    if (tid < nloc) {
        int node = nbase + tid;
        offsets[node] = e0 + excl;
        ends[node] = e0 + excl + myc;
        float r = rsqrtf(wsum[tid] + 1.0f);  // +1 = self-loop weight
        dinv[node] = r;
        // fused xscale: xs[node,:] = r * x[node,:]  (block-contiguous rows)
        const float4* xr = (const float4*)(x + (size_t)node * 8);
        float4* xo = (float4*)(xs + (size_t)node * 8);
        float4 a = xr[0], c = xr[1];
        a.x *= r; a.y *= r; a.z *= r; a.w *= r;
        c.x *= r; c.y *= r; c.z *= r; c.w *= r;
        xo[0] = a; xo[1] = c;
    }
    cnt[tid] = excl;  // cursor
    __syncthreads();
    for (int e = e0 + tid; e < e0 + ecnt; e += 512) {
        int2 p = ebuf[e];
        int dl = p.x >> 17;
        int pos = e0 + atomicAdd(&cnt[dl], 1);
        csr[pos] = make_int2(p.x & 0x1FFFF, p.y);  // (src, raw w)
    }
}

// ------- fused layer 0: 8-ch weighted-xs aggregation + 8x64 matvec + relu -------

__global__ void __launch_bounds__(256) k_gather0x(
        const float* __restrict__ xs, const int* __restrict__ offsets,
        const int* __restrict__ ends, const int2* __restrict__ csr,
        const float* __restrict__ dinv, const float* __restrict__ W0,
        const float* __restrict__ b0, bf16_t* __restrict__ rout) {
    __shared__ float Wsh[IN_DIM * 64];
    __shared__ float bsh[64];
    int tid = threadIdx.x;
    for (int i = tid; i < IN_DIM * 64; i += 256) Wsh[i] = W0[i];
    if (tid < 64) bsh[tid] = b0[tid];
    __syncthreads();
    int wid = (blockIdx.x * 256 + tid) >> 6;
    int lane = tid & 63;
    if (wid >= N_NODES) return;
    int k = lane & 7;      // channel
    int u = lane >> 3;     // edge slot
    float acc = (u == 0) ? xs[wid * 8 + k] : 0.0f;  // self term (w=1, pre-scaled)
    int e0 = offsets[wid], e1 = ends[wid];
    for (int base = e0; base < e1; base += 64) {
        int n = e1 - base;
        n = (n > 64) ? 64 : n;
        int2 pe = make_int2(wid, 0);  // pad: w=0
        if (lane < n) pe = csr[base + lane];
        int ng = (n + 7) >> 3;
        if (ng == 8) {
            int s[8]; float w[8], v[8];
#pragma unroll
            for (int g = 0; g < 8; ++g) {
                s[g] = __shfl(pe.x, g * 8 + u, 64);
                w[g] = __int_as_float(__shfl(pe.y, g * 8 + u, 64));
            }
#pragma unroll
            for (int g = 0; g < 8; ++g) v[g] = xs[s[g] * 8 + k];
#pragma unroll
            for (int g = 0; g < 8; ++g) acc = fmaf(w[g], v[g], acc);
        } else {
            for (int g = 0; g < ng; ++g) {
                int s = __shfl(pe.x, g * 8 + u, 64);
                float w = __int_as_float(__shfl(pe.y, g * 8 + u, 64));
                acc = fmaf(w, xs[s * 8 + k], acc);
            }
        }
    }
    acc += __shfl_xor(acc, 8, 64);
    acc += __shfl_xor(acc, 16, 64);
    acc += __shfl_xor(acc, 32, 64);
    float a[8];
#pragma unroll
    for (int kk = 0; kk < 8; ++kk) a[kk] = __shfl(acc, kk, 8);
    float t = 0.0f;
#pragma unroll
    for (int kk = 0; kk < 8; ++kk) t = fmaf(a[kk], Wsh[kk * 64 + lane], t);
    float rv = fmaxf(fmaf(t, dinv[wid], bsh[lane]), 0.0f);
    rout[(size_t)wid * 64 + lane] = f2bf(rv);
}

// ------- affmm: u' = dinv ∘ (affine(r) @ W), bf16 in/out (32 rows/block) -------

__global__ void __launch_bounds__(256) k_affmm(
        const bf16_t* __restrict__ r, const float* __restrict__ dinv,
        const float* __restrict__ statsin, const float* __restrict__ gamma,
        const float* __restrict__ beta, const float* __restrict__ W,
        bf16_t* __restrict__ out) {
    __shared__ float Wsh[64 * 64];
    __shared__ float hsh[32 * 64];
    __shared__ float scs[64], shs[64];
    __shared__ float din[32];
    int tid = threadIdx.x;
    if (tid < 64) {
        float s = 0.0f, q = 0.0f;
#pragma unroll
        for (int b = 0; b < 8; ++b) {
            s += statsin[b * 128 + tid];
            q += statsin[b * 128 + 64 + tid];
        }
        const float invn = 1.0f / (float)N_NODES;
        float mu = s * invn;
        float var = q * invn - mu * mu;
        float rs = rsqrtf(var + BN_EPS);
        float sc = gamma[tid] * rs;
        scs[tid] = sc;
        shs[tid] = beta[tid] - sc * mu;
    }
    {
        const float4* W4 = (const float4*)W;
        float4* Wsh4 = (float4*)Wsh;
        for (int i = tid; i < 1024; i += 256) Wsh4[i] = W4[i];
    }
    int row0 = blockIdx.x * 32;
    if (tid >= 224) din[tid - 224] = dinv[row0 + tid - 224];
    __syncthreads();
    {
        const ushort2* r2 = (const ushort2*)(r + (size_t)row0 * 64);
        for (int i = tid; i < 1024; i += 256) {
            ushort2 u = r2[i];
            int base = 2 * i;
            int kk = base & 63;
            hsh[base] = fmaf(bf2f(u.x), scs[kk], shs[kk]);
            hsh[base + 1] = fmaf(bf2f(u.y), scs[kk + 1], shs[kk + 1]);
        }
    }
    __syncthreads();
    int c = tid & 63, rsl = tid >> 6;
    float acc[8];
#pragma unroll
    for (int j = 0; j < 8; ++j) acc[j] = 0.0f;
    for (int k = 0; k < 64; k += 4) {
        float w0 = Wsh[(k + 0) * 64 + c];
        float w1 = Wsh[(k + 1) * 64 + c];
        float w2 = Wsh[(k + 2) * 64 + c];
        float w3 = Wsh[(k + 3) * 64 + c];
#pragma unroll
        for (int j = 0; j < 8; ++j) {
            float4 hv = *(const float4*)&hsh[(rsl * 8 + j) * 64 + k];
            acc[j] = fmaf(hv.x, w0, fmaf(hv.y, w1, fmaf(hv.z, w2, fmaf(hv.w, w3, acc[j]))));
        }
    }
#pragma unroll
    for (int j = 0; j < 8; ++j) {
        int rr = rsl * 8 + j;
        out[(size_t)(row0 + rr) * 64 + c] = f2bf(acc[j] * din[rr]);
    }
}

// ------- gather: r = relu(dinv[d]*(u'[d] + sum w*u'[s]) + bias), bf16 in/out -------

__global__ void __launch_bounds__(256) k_gather(
        const bf16_t* __restrict__ t, const int* __restrict__ offsets,
        const int* __restrict__ ends, const int2* __restrict__ csr,
        const float* __restrict__ dinv, const float* __restrict__ bias,
        bf16_t* __restrict__ rout) {
    int wid = (blockIdx.x * 256 + threadIdx.x) >> 6;
    int lane = threadIdx.x & 63;
    if (wid >= N_NODES) return;
    float acc = bf2f(t[(size_t)wid * 64 + lane]);  // self edge, w=1
    int e0 = offsets[wid], e1 = ends[wid];
    for (int base = e0; base < e1; base += 64) {
        int n = e1 - base;
        n = (n > 64) ? 64 : n;
        int2 pe = make_int2(wid, 0);  // pad: own row, weight 0
        if (lane < n) pe = csr[base + lane];
        int ng = (n + 7) >> 3;
        for (int g = 0; g < ng; ++g) {
            int j = g * 8;
            int s[8];
            float w[8];
#pragma unroll
            for (int u = 0; u < 8; ++u) {
                s[u] = __shfl(pe.x, j + u, 64);
                w[u] = __int_as_float(__shfl(pe.y, j + u, 64));
            }
            float v[8];
#pragma unroll
            for (int u = 0; u < 8; ++u) v[u] = bf2f(t[(size_t)s[u] * 64 + lane]);
#pragma unroll
            for (int u = 0; u < 8; ++u) acc = fmaf(w[u], v[u], acc);
        }
    }
    float rv = fmaxf(fmaf(acc, dinv[wid], bias[lane]), 0.0f);
    rout[(size_t)wid * 64 + lane] = f2bf(rv);
}

// ------- BN stats, vectorized uint4 loads, 8-binned (grid-stride, 1024 blocks) -------

__global__ void __launch_bounds__(256) k_bnstats(const bf16_t* __restrict__ r,
                                                 float* __restrict__ statsout) {
    __shared__ float sst[64], ssq[64];
    int tid = threadIdx.x;
    if (tid < 64) { sst[tid] = 0.0f; ssq[tid] = 0.0f; }
    int ch = tid & 7;       // channel chunk (8 bf16 = 16B)
    int slot = tid >> 3;    // row slot 0..31
    float sum[8], sq[8];
#pragma unroll
    for (int j = 0; j < 8; ++j) { sum[j] = 0.0f; sq[j] = 0.0f; }
    __syncthreads();
    for (int tile = blockIdx.x; tile < NTILES; tile += gridDim.x) {
        int row = tile * 32 + slot;
        uint4 v = *(const uint4*)(r + (size_t)row * 64 + ch * 8);
        unsigned int* vp = (unsigned int*)&v;
#pragma unroll
        for (int q = 0; q < 4; ++q) {
            float lo = __uint_as_float(vp[q] << 16);
            float hi = __uint_as_float(vp[q] & 0xffff0000u);
            sum[2 * q] += lo; sq[2 * q] += lo * lo;
            sum[2 * q + 1] += hi; sq[2 * q + 1] += hi * hi;
        }
    }
#pragma unroll
    for (int j = 0; j < 8; ++j) {
        atomicAdd(&sst[ch * 8 + j], sum[j]);
        atomicAdd(&ssq[ch * 8 + j], sq[j]);
    }
    __syncthreads();
    if (tid < 64) {
        int bin = blockIdx.x & 7;
        atomicAdd(&statsout[bin * 128 + tid], sst[tid]);
        atomicAdd(&statsout[bin * 128 + 64 + tid], ssq[tid]);
    }
}

// ------- pooling over sorted batch (run-length) + fused layer-2 BN stats -------

__global__ void __launch_bounds__(256) k_pool(const int* __restrict__ batch,
                                              const bf16_t* __restrict__ h,
                                              float* __restrict__ pooled,
                                              int* __restrict__ gcount,
                                              float* __restrict__ statsout) {
    __shared__ float s1[256], s2[256];
    int tid = threadIdx.x;
    int c = tid & 63;
    int wsub = tid >> 6;  // 0..3
    int start = blockIdx.x * POOL_ROWS;
    int end = start + POOL_ROWS; if (end > N_NODES) end = N_NODES;
    int cur = -1, cnt = 0;
    float acc = 0.0f, sum = 0.0f, ssq = 0.0f;
    for (int r = start + wsub; r < end; r += 4) {
        int g = batch[r];
        float v = bf2f(h[(size_t)r * 64 + c]);
        if (g != cur) {
            if (cur >= 0) {
                atomicAdd(&pooled[cur * 64 + c], acc);
                if (c == 0) atomicAdd(&gcount[cur], cnt);
            }
            cur = g; acc = 0.0f; cnt = 0;
        }
        acc += v; cnt += 1;
        sum += v; ssq += v * v;
    }
    if (cur >= 0) {
        atomicAdd(&pooled[cur * 64 + c], acc);
        if (c == 0) atomicAdd(&gcount[cur], cnt);
    }
    s1[tid] = sum; s2[tid] = ssq;
    __syncthreads();
    if (tid < 64) {
        int bin = blockIdx.x & 7;
        atomicAdd(&statsout[bin * 128 + tid],
                  s1[tid] + s1[tid + 64] + s1[tid + 128] + s1[tid + 192]);
        atomicAdd(&statsout[bin * 128 + 64 + tid],
                  s2[tid] + s2[tid + 64] + s2[tid + 128] + s2[tid + 192]);
    }
}

// ------- head: BN affine from binned stats folded via counts, mlp, log_softmax -------

__global__ void k_head(const float* __restrict__ pooled, const int* __restrict__ gcount,
                       const float* __restrict__ stats, const float* __restrict__ gamma,
                       const float* __restrict__ beta, const float* __restrict__ w1,
                       const float* __restrict__ b1, const float* __restrict__ w2,
                       const float* __restrict__ b2, float* __restrict__ out) {
    __shared__ float p[64];
    __shared__ float hid[64];
    __shared__ float o[2];
    int g = blockIdx.x, c = threadIdx.x;
    float s = 0.0f, q = 0.0f;
#pragma unroll
    for (int b = 0; b < 8; ++b) {
        s += stats[b * 128 + c];
        q += stats[b * 128 + 64 + c];
    }
    const float invn = 1.0f / (float)N_NODES;
    float mu = s * invn;
    float var = q * invn - mu * mu;
    float rs = rsqrtf(var + BN_EPS);
    float sc = gamma[c] * rs;
    float sh = beta[c] - sc * mu;
    p[c] = sc * pooled[g * 64 + c] + (float)gcount[g] * sh;
    __syncthreads();
    float acc = b1[c];
#pragma unroll
    for (int k = 0; k < 64; ++k) acc += p[k] * w1[k * 64 + c];
    hid[c] = fmaxf(acc, 0.0f);
    __syncthreads();
    if (c < 2) {
        float a = b2[c];
#pragma unroll
        for (int k = 0; k < 64; ++k) a += hid[k] * w2[k * 2 + c];
        o[c] = a;
    }
    __syncthreads();
    if (c == 0) {
        float m = fmaxf(o[0], o[1]);
        float l = m + logf(expf(o[0] - m) + expf(o[1] - m));
        out[g * 2 + 0] = o[0] - l;
        out[g * 2 + 1] = o[1] - l;
    }
}

extern "C" void kernel_launch(void* const* d_in, const int* in_sizes, int n_in,
                              void* d_out, int out_size, void* d_ws, size_t ws_size,
                              hipStream_t stream) {
    const float* x        = (const float*)d_in[0];
    const int*   ei       = (const int*)d_in[1];
    const int*   batch    = (const int*)d_in[2];
    const float* edge_attr= (const float*)d_in[3];
    const float* W0       = (const float*)d_in[4];
    const float* b0       = (const float*)d_in[5];
    const float* Ws       = (const float*)d_in[6];
    const float* bs       = (const float*)d_in[7];
    const float* gammas   = (const float*)d_in[8];
    const float* betas    = (const float*)d_in[9];
    const float* lin1_w   = (const float*)d_in[10];
    const float* lin1_b   = (const float*)d_in[11];
    const float* lin2_w   = (const float*)d_in[12];
    const float* lin2_b   = (const float*)d_in[13];
    float* out = (float*)d_out;

    const int* src = ei;
    const int* dst = ei + N_EDGES;

    // workspace layout (float units). csr/ebuf: NBUCK*BCAP int2 = 3,211,264 floats.
    float*  ws0      = (float*)d_ws;
    float*  dinv     = ws0;                             // [0, 100004)
    int*    offsets  = (int*)(ws0 + 100004);            // [100004, 200008)
    int*    ends     = (int*)(ws0 + 200008);            // [200008, 300012)
    int2*   csr      = (int2*)(ws0 + 300012);           // [300012, 3511276)
    bf16_t* tB       = (bf16_t*)(ws0 + 3511276);        // [3511276, 6711276)  u' rows
    bf16_t* rA       = (bf16_t*)(ws0 + 6711276);        // [6711276, 9911276)  r rows
    float*  stats    = ws0 + 9911276;                   // 3*1024
    float*  pooled   = stats + 3 * 1024;                // 16384
    int*    gcount   = (int*)(pooled + NGRAPH * 64);    // 256
    int*    bucket_cursor = (int*)(gcount + NGRAPH);    // 196 (zero-init by memset)
    float*  xs       = (float*)(bucket_cursor + 196);   // N*8 = 800000
    // transient alias: ebuf spans tB and the start of rA (dead after k_bsort;
    // tB first written by layer-1 affmm, rA by gather0x — both after bsort)
    int2*  ebuf = (int2*)tB;

    const int nblk_g   = N_NODES * 64 / 256;   // 25000 (wave per node)
    const int nblk_mm  = NTILES;               // 3125

    // one memset: stats + pooled + gcount + bucket_cursor (contiguous)
    hipMemsetAsync(stats, 0, (3 * 1024 + NGRAPH * 64 + NGRAPH + NBUCK) * sizeof(float),
                   stream);

    // ---- CSR build: bucket fill -> in-bucket sort (fused xscale) ----
    k_bfill<<<NBLK_B, 256, 0, stream>>>(src, dst, (const float2*)edge_attr,
                                        bucket_cursor, ebuf);
    k_bsort<<<NBUCK, 512, 0, stream>>>(bucket_cursor, ebuf, offsets, ends, csr,
                                       dinv, x, xs);

    // ---- layer 0: fused aggregation + 8x64 matvec -> r0 ----
    k_gather0x<<<nblk_g, 256, 0, stream>>>(xs, offsets, ends, csr, dinv, W0, b0, rA);
    k_bnstats<<<1024, 256, 0, stream>>>(rA, stats);

    // ---- layer 1 ----
    k_affmm<<<nblk_mm, 256, 0, stream>>>(rA, dinv, stats, gammas, betas, Ws, tB);
    k_gather<<<nblk_g, 256, 0, stream>>>(tB, offsets, ends, csr, dinv, bs, rA);
    k_bnstats<<<1024, 256, 0, stream>>>(rA, stats + 1024);

    // ---- layer 2 ----
    k_affmm<<<nblk_mm, 256, 0, stream>>>(rA, dinv, stats + 1024, gammas + 64, betas + 64,
                                         Ws + 64 * 64, tB);
    k_gather<<<nblk_g, 256, 0, stream>>>(tB, offsets, ends, csr, dinv, bs + 64, rA);

    // ---- pool (+ fused layer-2 stats) + head ----
    k_pool<<<(N_NODES + POOL_ROWS - 1) / POOL_ROWS, 256, 0, stream>>>(
        batch, rA, pooled, gcount, stats + 2048);
    k_head<<<NGRAPH, 64, 0, stream>>>(pooled, gcount, stats + 2048,
                                      gammas + 2 * 64, betas + 2 * 64,
                                      lin1_w, lin1_b, lin2_w, lin2_b, out);
}